// Round 1
// baseline (1874.425 us; speedup 1.0000x reference)
//
#include <hip/hip_runtime.h>
#include <math.h>

// Problem constants
#define TT 2048
#define EE 1024
#define HH 16
#define DH 64
// q/k/v buffers are [H][T][DH] fp32

// ---------------------------------------------------------------------------
// Tiled fp32 GEMM: C[m][n] = sum_k A[m][k] * B[n][k]   (both K-contiguous)
// BM=BN=64, BK=16, 256 threads, each thread computes 4x4.
// EPI==0: plain row-major C write. EPI==1: scatter into q/k/v [H][T][DH].
// ---------------------------------------------------------------------------
template <int EPI>
__global__ __launch_bounds__(256) void gemm_tn(
    const float* __restrict__ A, const float* __restrict__ B,
    float* __restrict__ C, float* __restrict__ qb, float* __restrict__ kb,
    float* __restrict__ vb, int M, int N, int K) {
  __shared__ __attribute__((aligned(16))) float As[16][68];  // 68*4=272B = 17*16, rows stay 16B-aligned
  __shared__ __attribute__((aligned(16))) float Bs[16][68];

  const int tid = threadIdx.x;
  const int tx = tid & 15;   // n direction
  const int ty = tid >> 4;   // m direction
  const int r = tid >> 2;    // 0..63  load row
  const int c = tid & 3;     // 0..3   load k-chunk

  const int m0 = blockIdx.y * 64;
  const int n0 = blockIdx.x * 64;

  float acc[4][4];
#pragma unroll
  for (int i = 0; i < 4; i++)
#pragma unroll
    for (int j = 0; j < 4; j++) acc[i][j] = 0.f;

  for (int k0 = 0; k0 < K; k0 += 16) {
    float4 a = *(const float4*)&A[(size_t)(m0 + r) * K + k0 + c * 4];
    float4 b = *(const float4*)&B[(size_t)(n0 + r) * K + k0 + c * 4];
    __syncthreads();  // protect previous iteration's reads
    As[c * 4 + 0][r] = a.x; As[c * 4 + 1][r] = a.y;
    As[c * 4 + 2][r] = a.z; As[c * 4 + 3][r] = a.w;
    Bs[c * 4 + 0][r] = b.x; Bs[c * 4 + 1][r] = b.y;
    Bs[c * 4 + 2][r] = b.z; Bs[c * 4 + 3][r] = b.w;
    __syncthreads();
#pragma unroll
    for (int kk = 0; kk < 16; kk++) {
      float4 av = *(const float4*)&As[kk][ty * 4];
      float4 bv = *(const float4*)&Bs[kk][tx * 4];
      acc[0][0] = fmaf(av.x, bv.x, acc[0][0]);
      acc[0][1] = fmaf(av.x, bv.y, acc[0][1]);
      acc[0][2] = fmaf(av.x, bv.z, acc[0][2]);
      acc[0][3] = fmaf(av.x, bv.w, acc[0][3]);
      acc[1][0] = fmaf(av.y, bv.x, acc[1][0]);
      acc[1][1] = fmaf(av.y, bv.y, acc[1][1]);
      acc[1][2] = fmaf(av.y, bv.z, acc[1][2]);
      acc[1][3] = fmaf(av.y, bv.w, acc[1][3]);
      acc[2][0] = fmaf(av.z, bv.x, acc[2][0]);
      acc[2][1] = fmaf(av.z, bv.y, acc[2][1]);
      acc[2][2] = fmaf(av.z, bv.z, acc[2][2]);
      acc[2][3] = fmaf(av.z, bv.w, acc[2][3]);
      acc[3][0] = fmaf(av.w, bv.x, acc[3][0]);
      acc[3][1] = fmaf(av.w, bv.y, acc[3][1]);
      acc[3][2] = fmaf(av.w, bv.z, acc[3][2]);
      acc[3][3] = fmaf(av.w, bv.w, acc[3][3]);
    }
  }

  if (EPI == 0) {
#pragma unroll
    for (int i = 0; i < 4; i++) {
      float4 v4 = make_float4(acc[i][0], acc[i][1], acc[i][2], acc[i][3]);
      *(float4*)&C[(size_t)(m0 + ty * 4 + i) * N + n0 + tx * 4] = v4;
    }
  } else {
    // n -> which (q/k/v), head, dim.  n-chunk of 4 never crosses a head.
    const int n_base = n0 + tx * 4;
    const int which = n_base >> 10;
    const int e = n_base & 1023;
    const int h = e >> 6;
    const int d = e & 63;
    float* dst = (which == 0) ? qb : (which == 1) ? kb : vb;
#pragma unroll
    for (int i = 0; i < 4; i++) {
      const int m = m0 + ty * 4 + i;
      float4 v4 = make_float4(acc[i][0], acc[i][1], acc[i][2], acc[i][3]);
      *(float4*)&dst[((size_t)h * TT + m) * DH + d] = v4;
    }
  }
}

// ---------------------------------------------------------------------------
// RoPE cos/sin table: [T][32].  Angle computed in fp32 (matches reference
// rounding of t * inv_freq); sin/cos evaluated in double (accurate like JAX).
// ---------------------------------------------------------------------------
__global__ void rope_table(float* __restrict__ cs, float* __restrict__ sn) {
  int i = blockIdx.x * 256 + threadIdx.x;  // < 2048*32
  int t = i >> 5;
  int d = i & 31;
  float inv = powf(10000.f, -((float)d) / 32.f);
  float ang = (float)t * inv;
  cs[i] = (float)cos((double)ang);
  sn[i] = (float)sin((double)ang);
}

// ---------------------------------------------------------------------------
// In-place RoPE on q and k ([H][T][DH]); pairs (d, d+32), d<32.
// ---------------------------------------------------------------------------
__global__ void rope_apply(float* __restrict__ qb, float* __restrict__ kb,
                           const float* __restrict__ cs,
                           const float* __restrict__ sn) {
  int id = blockIdx.x * 256 + threadIdx.x;  // < 2 * H*T*32
  const int n = HH * TT * 32;               // 1,048,576
  int which = id >= n;
  int i = which ? id - n : id;
  float* p = which ? kb : qb;
  int h = i >> 16;          // / (T*32)
  int rem = i & 65535;
  int t = rem >> 5;
  int d = rem & 31;
  size_t off = ((size_t)h * TT + t) * DH + d;
  float c = cs[rem];  // index t*32+d
  float s = sn[rem];
  float a = p[off];
  float b = p[off + 32];
  p[off] = a * c - b * s;
  p[off + 32] = b * c + a * s;
}

// ---------------------------------------------------------------------------
// Causal attention, fp32.  One wave per (head, query row).
// Online softmax over 64-key chunks; lane owns one key/chunk for scores
// (q broadcast from LDS), lane owns one output dim for PV (p via __shfl).
// ---------------------------------------------------------------------------
__global__ __launch_bounds__(256) void attn_fp32(
    const float* __restrict__ Q, const float* __restrict__ K,
    const float* __restrict__ V, float* __restrict__ O) {
  __shared__ __attribute__((aligned(16))) float q_lds[4][64];
  const int tid = threadIdx.x;
  const int wv = tid >> 6;
  const int lane = tid & 63;
  const int w = blockIdx.x * 4 + wv;  // 0 .. H*T-1
  const int h = w >> 11;              // / T
  const int t = w & (TT - 1);

  q_lds[wv][lane] = Q[((size_t)h * TT + t) * DH + lane];
  __syncthreads();
  const float4* q4 = reinterpret_cast<const float4*>(&q_lds[wv][0]);

  float m = -1e30f, l = 0.f, o = 0.f;
  const int nchunk = (t >> 6) + 1;
  for (int i = 0; i < nchunk; i++) {
    const int sbase = i << 6;
    const int s = sbase + lane;
    float sc = -1e30f;
    if (s <= t) {
      const float4* krow =
          reinterpret_cast<const float4*>(K + ((size_t)h * TT + s) * DH);
      float a0 = 0.f;
#pragma unroll
      for (int cc = 0; cc < 16; cc++) {
        float4 kk = krow[cc];
        float4 qq = q4[cc];
        a0 = fmaf(kk.x, qq.x, a0);
        a0 = fmaf(kk.y, qq.y, a0);
        a0 = fmaf(kk.z, qq.z, a0);
        a0 = fmaf(kk.w, qq.w, a0);
      }
      sc = a0 * 0.125f;  // 1/sqrt(64)
    }
    // chunk max (wave allreduce)
    float cm = sc;
#pragma unroll
    for (int off = 32; off; off >>= 1) cm = fmaxf(cm, __shfl_xor(cm, off));
    const float mn = fmaxf(m, cm);
    const float corr = expf(m - mn);  // first iter: expf(-inf) = 0
    const float p = expf(sc - mn);    // invalid lanes: expf(-inf) = 0
    float ps = p;
#pragma unroll
    for (int off = 32; off; off >>= 1) ps += __shfl_xor(ps, off);
    l = l * corr + ps;
    o = o * corr;
    m = mn;
    // PV: lane owns output dim = lane; broadcast p of key sbase+j from lane j
    const int jmax = min(63, t - sbase);
    const float* vcol = V + ((size_t)h * TT + sbase) * DH + lane;
    for (int j = 0; j <= jmax; j++) {
      float pj = __shfl(p, j);
      o = fmaf(pj, vcol[(size_t)j * DH], o);
    }
  }
  O[(size_t)t * EE + h * DH + lane] = o / l;
}

// ---------------------------------------------------------------------------
extern "C" void kernel_launch(void* const* d_in, const int* in_sizes, int n_in,
                              void* d_out, int out_size, void* d_ws,
                              size_t ws_size, hipStream_t stream) {
  const float* x = (const float*)d_in[0];    // [2048][1024]
  const float* W1 = (const float*)d_in[1];   // [3072][1024]
  const float* W2 = (const float*)d_in[2];   // [1024][1024]
  float* out = (float*)d_out;                // [2048][1024]

  float* ws = (float*)d_ws;
  const size_t HTD = (size_t)HH * TT * DH;   // 2,097,152
  float* qb = ws;
  float* kb = qb + HTD;
  float* vb = kb + HTD;
  float* ob = vb + HTD;                      // [T][E]
  float* cs = ob + (size_t)TT * EE;
  float* sn = cs + (size_t)TT * 32;

  // 1. RoPE table (independent; launch first)
  rope_table<<<(TT * 32) / 256, 256, 0, stream>>>(cs, sn);
  // 2. QKV GEMM with scatter into [H][T][DH]
  gemm_tn<1><<<dim3(3 * EE / 64, TT / 64), 256, 0, stream>>>(
      x, W1, nullptr, qb, kb, vb, TT, 3 * EE, EE);
  // 3. RoPE on q and k (in place)
  rope_apply<<<(2 * HH * TT * 32) / 256, 256, 0, stream>>>(qb, kb, cs, sn);
  // 4. Causal attention
  attn_fp32<<<(HH * TT) / 4, 256, 0, stream>>>(qb, kb, vb, ob);
  // 5. Output projection
  gemm_tn<0><<<dim3(EE / 64, TT / 64), 256, 0, stream>>>(
      ob, W2, out, nullptr, nullptr, nullptr, TT, EE, EE);
}

// Round 4
// 532.277 us; speedup vs baseline: 3.5215x; 3.5215x over previous
//
#include <hip/hip_runtime.h>
#include <math.h>

// Problem constants
#define TT 2048
#define EE 1024
#define HH 16
#define DH 64
// q/k/v buffers are [H][T][DH] fp32

// ---------------------------------------------------------------------------
// Tiled fp32 GEMM: C[m][n] = sum_k A[m][k] * B[n][k]   (both K-contiguous)
// BM=BN=64, BK=16, 256 threads, each thread computes 4x4.
// EPI==0: plain row-major C write. EPI==1: scatter into q/k/v [H][T][DH].
// ---------------------------------------------------------------------------
template <int EPI>
__global__ __launch_bounds__(256) void gemm_tn(
    const float* __restrict__ A, const float* __restrict__ B,
    float* __restrict__ C, float* __restrict__ qb, float* __restrict__ kb,
    float* __restrict__ vb, int M, int N, int K) {
  __shared__ __attribute__((aligned(16))) float As[16][68];
  __shared__ __attribute__((aligned(16))) float Bs[16][68];

  const int tid = threadIdx.x;
  const int tx = tid & 15;   // n direction
  const int ty = tid >> 4;   // m direction
  const int r = tid >> 2;    // 0..63  load row
  const int c = tid & 3;     // 0..3   load k-chunk

  const int m0 = blockIdx.y * 64;
  const int n0 = blockIdx.x * 64;

  float acc[4][4];
#pragma unroll
  for (int i = 0; i < 4; i++)
#pragma unroll
    for (int j = 0; j < 4; j++) acc[i][j] = 0.f;

  for (int k0 = 0; k0 < K; k0 += 16) {
    float4 a = *(const float4*)&A[(size_t)(m0 + r) * K + k0 + c * 4];
    float4 b = *(const float4*)&B[(size_t)(n0 + r) * K + k0 + c * 4];
    __syncthreads();  // protect previous iteration's reads
    As[c * 4 + 0][r] = a.x; As[c * 4 + 1][r] = a.y;
    As[c * 4 + 2][r] = a.z; As[c * 4 + 3][r] = a.w;
    Bs[c * 4 + 0][r] = b.x; Bs[c * 4 + 1][r] = b.y;
    Bs[c * 4 + 2][r] = b.z; Bs[c * 4 + 3][r] = b.w;
    __syncthreads();
#pragma unroll
    for (int kk = 0; kk < 16; kk++) {
      float4 av = *(const float4*)&As[kk][ty * 4];
      float4 bv = *(const float4*)&Bs[kk][tx * 4];
      acc[0][0] = fmaf(av.x, bv.x, acc[0][0]);
      acc[0][1] = fmaf(av.x, bv.y, acc[0][1]);
      acc[0][2] = fmaf(av.x, bv.z, acc[0][2]);
      acc[0][3] = fmaf(av.x, bv.w, acc[0][3]);
      acc[1][0] = fmaf(av.y, bv.x, acc[1][0]);
      acc[1][1] = fmaf(av.y, bv.y, acc[1][1]);
      acc[1][2] = fmaf(av.y, bv.z, acc[1][2]);
      acc[1][3] = fmaf(av.y, bv.w, acc[1][3]);
      acc[2][0] = fmaf(av.z, bv.x, acc[2][0]);
      acc[2][1] = fmaf(av.z, bv.y, acc[2][1]);
      acc[2][2] = fmaf(av.z, bv.z, acc[2][2]);
      acc[2][3] = fmaf(av.z, bv.w, acc[2][3]);
      acc[3][0] = fmaf(av.w, bv.x, acc[3][0]);
      acc[3][1] = fmaf(av.w, bv.y, acc[3][1]);
      acc[3][2] = fmaf(av.w, bv.z, acc[3][2]);
      acc[3][3] = fmaf(av.w, bv.w, acc[3][3]);
    }
  }

  if (EPI == 0) {
#pragma unroll
    for (int i = 0; i < 4; i++) {
      float4 v4 = make_float4(acc[i][0], acc[i][1], acc[i][2], acc[i][3]);
      *(float4*)&C[(size_t)(m0 + ty * 4 + i) * N + n0 + tx * 4] = v4;
    }
  } else {
    const int n_base = n0 + tx * 4;
    const int which = n_base >> 10;
    const int e = n_base & 1023;
    const int h = e >> 6;
    const int d = e & 63;
    float* dst = (which == 0) ? qb : (which == 1) ? kb : vb;
#pragma unroll
    for (int i = 0; i < 4; i++) {
      const int m = m0 + ty * 4 + i;
      float4 v4 = make_float4(acc[i][0], acc[i][1], acc[i][2], acc[i][3]);
      *(float4*)&dst[((size_t)h * TT + m) * DH + d] = v4;
    }
  }
}

// ---------------------------------------------------------------------------
// RoPE cos/sin table: [T][32].
// ---------------------------------------------------------------------------
__global__ void rope_table(float* __restrict__ cs, float* __restrict__ sn) {
  int i = blockIdx.x * 256 + threadIdx.x;  // < 2048*32
  int t = i >> 5;
  int d = i & 31;
  float inv = powf(10000.f, -((float)d) / 32.f);
  float ang = (float)t * inv;
  cs[i] = (float)cos((double)ang);
  sn[i] = (float)sin((double)ang);
}

// ---------------------------------------------------------------------------
// In-place RoPE on q and k ([H][T][DH]); pairs (d, d+32), d<32.
// ---------------------------------------------------------------------------
__global__ void rope_apply(float* __restrict__ qb, float* __restrict__ kb,
                           const float* __restrict__ cs,
                           const float* __restrict__ sn) {
  int id = blockIdx.x * 256 + threadIdx.x;  // < 2 * H*T*32
  const int n = HH * TT * 32;               // 1,048,576
  int which = id >= n;
  int i = which ? id - n : id;
  float* p = which ? kb : qb;
  int h = i >> 16;
  int rem = i & 65535;
  size_t off = ((size_t)h * TT) * DH + (rem >> 5) * DH + (rem & 31);
  float c = cs[rem];
  float s = sn[rem];
  float a = p[off];
  float b = p[off + 32];
  p[off] = a * c - b * s;
  p[off + 32] = b * c + a * s;
}

// ---------------------------------------------------------------------------
// Tiled flash attention, fp32.  One 64-query tile per 256-thread block.
// Iterate 64-key chunks: stage K (transposed, d-major) and V (k-major) in
// LDS, register-tiled 64x64x64 QK^T (4x4 per thread), online softmax with
// 16-lane shfl row reduce, P transposed to LDS, register-tiled PV.
// Grid 512 = 16 heads x 32 tiles; tile map pairs heavy+light on one CU.
// ---------------------------------------------------------------------------
__global__ __launch_bounds__(256) void attn_tile(
    const float* __restrict__ Q, const float* __restrict__ K,
    const float* __restrict__ V, float* __restrict__ O) {
  __shared__ __attribute__((aligned(16))) float Qs[64][68];  // [d][q], prescaled
  __shared__ __attribute__((aligned(16))) float Ks[64][68];  // [d][k]
  __shared__ __attribute__((aligned(16))) float Ps[64][68];  // [k][q]
  __shared__ __attribute__((aligned(16))) float Vs[64][72];  // [k][d]

  const int tid = threadIdx.x;
  const int tx = tid & 15;   // 4 cols (k in QK / d in PV)
  const int ty = tid >> 4;   // 4 rows (q)
  const int r = tid >> 2;    // staging row 0..63
  const int c = tid & 3;     // staging quad 0..3
  const int h = blockIdx.x & 15;
  const int idx = blockIdx.x >> 4;
  const int tile = (idx < 16) ? idx : 47 - idx;  // blocks b, b+256 sum to 33 chunks
  const int qbase = tile << 6;
  const int nc = tile + 1;

  const float* Qh = Q + (size_t)h * TT * DH;
  const float* Kh = K + (size_t)h * TT * DH;
  const float* Vh = V + (size_t)h * TT * DH;

  // Q tile -> Qs[d][q], prescaled by 1/sqrt(Dh)
#pragma unroll
  for (int p = 0; p < 4; p++) {
    const int d0 = p * 16 + c * 4;
    float4 q4 = *(const float4*)&Qh[(size_t)(qbase + r) * DH + d0];
    Qs[d0 + 0][r] = q4.x * 0.125f;
    Qs[d0 + 1][r] = q4.y * 0.125f;
    Qs[d0 + 2][r] = q4.z * 0.125f;
    Qs[d0 + 3][r] = q4.w * 0.125f;
  }

  float m[4], l[4], oacc[4][4];
#pragma unroll
  for (int i = 0; i < 4; i++) {
    m[i] = -1e30f;
    l[i] = 0.f;
#pragma unroll
    for (int j = 0; j < 4; j++) oacc[i][j] = 0.f;
  }

  // prefetch chunk 0
  float4 kst[4], vst[4];
#pragma unroll
  for (int p = 0; p < 4; p++) {
    const int d0 = p * 16 + c * 4;
    kst[p] = *(const float4*)&Kh[(size_t)r * DH + d0];
    vst[p] = *(const float4*)&Vh[(size_t)r * DH + d0];
  }

  for (int ch = 0; ch < nc; ch++) {
    __syncthreads();  // prev chunk's reads of Ks/Vs/Ps done (also Qs visibility)
    // stage K transposed, V direct
#pragma unroll
    for (int p = 0; p < 4; p++) {
      const int d0 = p * 16 + c * 4;
      Ks[d0 + 0][r] = kst[p].x;
      Ks[d0 + 1][r] = kst[p].y;
      Ks[d0 + 2][r] = kst[p].z;
      Ks[d0 + 3][r] = kst[p].w;
      *(float4*)&Vs[r][d0] = vst[p];
    }
    __syncthreads();
    // prefetch next chunk (redundant reload of current on last iter)
    {
      const int nb = ((ch + 1 < nc) ? ch + 1 : ch) << 6;
#pragma unroll
      for (int p = 0; p < 4; p++) {
        const int d0 = p * 16 + c * 4;
        kst[p] = *(const float4*)&Kh[(size_t)(nb + r) * DH + d0];
        vst[p] = *(const float4*)&Vh[(size_t)(nb + r) * DH + d0];
      }
    }
    // QK^T: sc[4][4]
    float sc[4][4];
#pragma unroll
    for (int i = 0; i < 4; i++)
#pragma unroll
      for (int j = 0; j < 4; j++) sc[i][j] = 0.f;
#pragma unroll 8
    for (int kk = 0; kk < 64; kk++) {
      float4 qv = *(const float4*)&Qs[kk][ty * 4];
      float4 kv = *(const float4*)&Ks[kk][tx * 4];
      sc[0][0] = fmaf(qv.x, kv.x, sc[0][0]);
      sc[0][1] = fmaf(qv.x, kv.y, sc[0][1]);
      sc[0][2] = fmaf(qv.x, kv.z, sc[0][2]);
      sc[0][3] = fmaf(qv.x, kv.w, sc[0][3]);
      sc[1][0] = fmaf(qv.y, kv.x, sc[1][0]);
      sc[1][1] = fmaf(qv.y, kv.y, sc[1][1]);
      sc[1][2] = fmaf(qv.y, kv.z, sc[1][2]);
      sc[1][3] = fmaf(qv.y, kv.w, sc[1][3]);
      sc[2][0] = fmaf(qv.z, kv.x, sc[2][0]);
      sc[2][1] = fmaf(qv.z, kv.y, sc[2][1]);
      sc[2][2] = fmaf(qv.z, kv.z, sc[2][2]);
      sc[2][3] = fmaf(qv.z, kv.w, sc[2][3]);
      sc[3][0] = fmaf(qv.w, kv.x, sc[3][0]);
      sc[3][1] = fmaf(qv.w, kv.y, sc[3][1]);
      sc[3][2] = fmaf(qv.w, kv.z, sc[3][2]);
      sc[3][3] = fmaf(qv.w, kv.w, sc[3][3]);
    }
    // causal mask on the diagonal chunk
    if (ch == tile) {
#pragma unroll
      for (int i = 0; i < 4; i++)
#pragma unroll
        for (int j = 0; j < 4; j++)
          if (tx * 4 + j > ty * 4 + i) sc[i][j] = -1e30f;
    }
    // online softmax per row (16 lanes share a row group)
    float pr[4][4];
#pragma unroll
    for (int i = 0; i < 4; i++) {
      float rm = fmaxf(fmaxf(sc[i][0], sc[i][1]), fmaxf(sc[i][2], sc[i][3]));
      rm = fmaxf(rm, __shfl_xor(rm, 1));
      rm = fmaxf(rm, __shfl_xor(rm, 2));
      rm = fmaxf(rm, __shfl_xor(rm, 4));
      rm = fmaxf(rm, __shfl_xor(rm, 8));
      const float mn = fmaxf(m[i], rm);
      const float corr = __expf(m[i] - mn);
      float rs = 0.f;
#pragma unroll
      for (int j = 0; j < 4; j++) {
        pr[i][j] = __expf(sc[i][j] - mn);
        rs += pr[i][j];
      }
      rs += __shfl_xor(rs, 1);
      rs += __shfl_xor(rs, 2);
      rs += __shfl_xor(rs, 4);
      rs += __shfl_xor(rs, 8);
      l[i] = l[i] * corr + rs;
      m[i] = mn;
      oacc[i][0] *= corr;
      oacc[i][1] *= corr;
      oacc[i][2] *= corr;
      oacc[i][3] *= corr;
    }
    // P -> LDS transposed [k][q]
#pragma unroll
    for (int i = 0; i < 4; i++)
#pragma unroll
      for (int j = 0; j < 4; j++) Ps[tx * 4 + j][ty * 4 + i] = pr[i][j];
    __syncthreads();
    // PV: oacc += P^T-tile @ V-chunk
#pragma unroll 8
    for (int kk = 0; kk < 64; kk++) {
      float4 pv = *(const float4*)&Ps[kk][ty * 4];
      float4 vv = *(const float4*)&Vs[kk][tx * 4];
      oacc[0][0] = fmaf(pv.x, vv.x, oacc[0][0]);
      oacc[0][1] = fmaf(pv.x, vv.y, oacc[0][1]);
      oacc[0][2] = fmaf(pv.x, vv.z, oacc[0][2]);
      oacc[0][3] = fmaf(pv.x, vv.w, oacc[0][3]);
      oacc[1][0] = fmaf(pv.y, vv.x, oacc[1][0]);
      oacc[1][1] = fmaf(pv.y, vv.y, oacc[1][1]);
      oacc[1][2] = fmaf(pv.y, vv.z, oacc[1][2]);
      oacc[1][3] = fmaf(pv.y, vv.w, oacc[1][3]);
      oacc[2][0] = fmaf(pv.z, vv.x, oacc[2][0]);
      oacc[2][1] = fmaf(pv.z, vv.y, oacc[2][1]);
      oacc[2][2] = fmaf(pv.z, vv.z, oacc[2][2]);
      oacc[2][3] = fmaf(pv.z, vv.w, oacc[2][3]);
      oacc[3][0] = fmaf(pv.w, vv.x, oacc[3][0]);
      oacc[3][1] = fmaf(pv.w, vv.y, oacc[3][1]);
      oacc[3][2] = fmaf(pv.w, vv.z, oacc[3][2]);
      oacc[3][3] = fmaf(pv.w, vv.w, oacc[3][3]);
    }
  }
  // epilogue: divide by l, write to [T][E]
#pragma unroll
  for (int i = 0; i < 4; i++) {
    const float inv = 1.f / l[i];
    float4 o4 = make_float4(oacc[i][0] * inv, oacc[i][1] * inv,
                            oacc[i][2] * inv, oacc[i][3] * inv);
    *(float4*)&O[(size_t)(qbase + ty * 4 + i) * EE + h * DH + tx * 4] = o4;
  }
}

// ---------------------------------------------------------------------------
extern "C" void kernel_launch(void* const* d_in, const int* in_sizes, int n_in,
                              void* d_out, int out_size, void* d_ws,
                              size_t ws_size, hipStream_t stream) {
  const float* x = (const float*)d_in[0];    // [2048][1024]
  const float* W1 = (const float*)d_in[1];   // [3072][1024]
  const float* W2 = (const float*)d_in[2];   // [1024][1024]
  float* out = (float*)d_out;                // [2048][1024]

  float* ws = (float*)d_ws;
  const size_t HTD = (size_t)HH * TT * DH;   // 2,097,152
  float* qb = ws;
  float* kb = qb + HTD;
  float* vb = kb + HTD;
  float* ob = vb + HTD;                      // [T][E]
  float* cs = ob + (size_t)TT * EE;
  float* sn = cs + (size_t)TT * 32;

  rope_table<<<(TT * 32) / 256, 256, 0, stream>>>(cs, sn);
  gemm_tn<1><<<dim3(3 * EE / 64, TT / 64), 256, 0, stream>>>(
      x, W1, nullptr, qb, kb, vb, TT, 3 * EE, EE);
  rope_apply<<<(2 * HH * TT * 32) / 256, 256, 0, stream>>>(qb, kb, cs, sn);
  attn_tile<<<512, 256, 0, stream>>>(qb, kb, vb, ob);
  gemm_tn<0><<<dim3(EE / 64, TT / 64), 256, 0, stream>>>(
      ob, W2, out, nullptr, nullptr, nullptr, TT, EE, EE);
}

// Round 8
// 362.194 us; speedup vs baseline: 5.1752x; 1.4696x over previous
//
#include <hip/hip_runtime.h>
#include <math.h>

// Problem constants
#define TT 2048
#define EE 1024
#define HH 16
#define DH 64
// q/k/v buffers are [H][T][DH] fp32

typedef unsigned short u16;
typedef __attribute__((ext_vector_type(8))) short bf16x8;   // 8 bf16 = 4 VGPRs
typedef __attribute__((ext_vector_type(4))) float f32x4;
typedef __attribute__((address_space(1))) unsigned int uint_g;
typedef __attribute__((address_space(3))) unsigned int uint_l;

// fp32 -> bf16 round-to-nearest-even
__device__ __forceinline__ u16 f2bf(float f) {
  unsigned u = __float_as_uint(f);
  u += 0x7fffu + ((u >> 16) & 1u);
  return (u16)(u >> 16);
}

// ---------------------------------------------------------------------------
// fp32 -> bf16 conversion, 8 elements/thread (n8 = n/8)
// ---------------------------------------------------------------------------
__global__ __launch_bounds__(256) void cvt_bf16(const float* __restrict__ s,
                                                u16* __restrict__ d, int n8) {
  int i = blockIdx.x * 256 + threadIdx.x;
  if (i >= n8) return;
  const float4* s4 = (const float4*)s;
  float4 a = s4[2 * i], b = s4[2 * i + 1];
  bf16x8 o;
  o[0] = (short)f2bf(a.x); o[1] = (short)f2bf(a.y);
  o[2] = (short)f2bf(a.z); o[3] = (short)f2bf(a.w);
  o[4] = (short)f2bf(b.x); o[5] = (short)f2bf(b.y);
  o[6] = (short)f2bf(b.z); o[7] = (short)f2bf(b.w);
  *(bf16x8*)&d[8 * i] = o;
}

// ---------------------------------------------------------------------------
// bf16 MFMA GEMM (TN): C[m][n] = sum_k A[m][k] * B[n][k], fp32 accum/output.
// 128x128 tile, BK=32, 256 threads = 4 waves (2x2), each wave 64x64 output
// = 4x4 fragments of mfma_f32_16x16x32_bf16.  global_load_lds (16B) staging.
// EPI==0: row-major C.  EPI==1: scatter into q/k/v [H][T][DH].
// ---------------------------------------------------------------------------
template <int EPI>
__global__ __launch_bounds__(256) void gemm_mfma(
    const u16* __restrict__ A, const u16* __restrict__ B, float* __restrict__ C,
    float* __restrict__ qb, float* __restrict__ kb, float* __restrict__ vb,
    int M, int N, int K) {
  __shared__ u16 smem[8192];  // As[128][32] @0 | Bs[128][32] @4096 (ushorts)
  const int tid = threadIdx.x;
  const int lane = tid & 63;
  const int wid = tid >> 6;
  const int wr = wid >> 1, wc = wid & 1;
  const int m0 = blockIdx.y * 128, n0 = blockIdx.x * 128;

  // staging: 4 x 16B per thread per K-step; precompute sources/dests
  const u16* gp[4];
  int lo[4];
#pragma unroll
  for (int q = 0; q < 4; q++) {
    int o = (wid * 4 + q) * 1024 + lane * 16;  // byte offset into smem
    lo[q] = o >> 1;
    if (o < 8192) {
      int row = o >> 6, col = (o >> 1) & 31;
      gp[q] = A + (size_t)(m0 + row) * K + col;
    } else {
      int o2 = o - 8192;
      int row = o2 >> 6, col = (o2 >> 1) & 31;
      gp[q] = B + (size_t)(n0 + row) * K + col;
    }
  }

  // fragment LDS offsets (ushort units): lane&15 = m/n row, 8 contig bf16 in k
  const int a_off = (wr * 64 + (lane & 15)) * 32 + (lane >> 4) * 8;
  const int b_off = 4096 + (wc * 64 + (lane & 15)) * 32 + (lane >> 4) * 8;

  f32x4 acc[4][4];
#pragma unroll
  for (int i = 0; i < 4; i++)
#pragma unroll
    for (int j = 0; j < 4; j++) acc[i][j] = f32x4{0.f, 0.f, 0.f, 0.f};

  for (int k0 = 0; k0 < K; k0 += 32) {
    __syncthreads();  // prior frag reads done before overwrite
#pragma unroll
    for (int q = 0; q < 4; q++) {
      __builtin_amdgcn_global_load_lds((const uint_g*)gp[q],
                                       (uint_l*)&smem[lo[q]], 16, 0, 0);
      gp[q] += 32;
    }
    __syncthreads();  // staging visible (vmcnt drained by barrier)
    bf16x8 af[4], bg[4];
#pragma unroll
    for (int i = 0; i < 4; i++) af[i] = *(const bf16x8*)&smem[a_off + i * 512];
#pragma unroll
    for (int j = 0; j < 4; j++) bg[j] = *(const bf16x8*)&smem[b_off + j * 512];
#pragma unroll
    for (int i = 0; i < 4; i++)
#pragma unroll
      for (int j = 0; j < 4; j++)
        acc[i][j] = __builtin_amdgcn_mfma_f32_16x16x32_bf16(af[i], bg[j],
                                                            acc[i][j], 0, 0, 0);
  }

  // epilogue: C/D layout col(n)=lane&15, row(m)=(lane>>4)*4+reg
  const int rbase = (lane >> 4) * 4;
  const int ncol = lane & 15;
  if (EPI == 0) {
#pragma unroll
    for (int i = 0; i < 4; i++) {
      int m = m0 + wr * 64 + i * 16 + rbase;
#pragma unroll
      for (int j = 0; j < 4; j++) {
        int n = n0 + wc * 64 + j * 16 + ncol;
#pragma unroll
        for (int r = 0; r < 4; r++) C[(size_t)(m + r) * N + n] = acc[i][j][r];
      }
    }
  } else {
#pragma unroll
    for (int j = 0; j < 4; j++) {
      int n = n0 + wc * 64 + j * 16 + ncol;
      int which = n >> 10, h = (n >> 6) & 15, d = n & 63;
      float* dst = (which == 0) ? qb : (which == 1) ? kb : vb;
#pragma unroll
      for (int i = 0; i < 4; i++) {
        int m = m0 + wr * 64 + i * 16 + rbase;
#pragma unroll
        for (int r = 0; r < 4; r++)
          dst[((size_t)h * TT + m + r) * DH + d] = acc[i][j][r];
      }
    }
  }
}

// ---------------------------------------------------------------------------
// RoPE cos/sin table: [T][32].
// ---------------------------------------------------------------------------
__global__ void rope_table(float* __restrict__ cs, float* __restrict__ sn) {
  int i = blockIdx.x * 256 + threadIdx.x;  // < 2048*32
  int t = i >> 5;
  int d = i & 31;
  float inv = powf(10000.f, -((float)d) / 32.f);
  float ang = (float)t * inv;
  cs[i] = (float)cos((double)ang);
  sn[i] = (float)sin((double)ang);
}

// ---------------------------------------------------------------------------
// In-place RoPE on q and k ([H][T][DH]); pairs (d, d+32), d<32.
// ---------------------------------------------------------------------------
__global__ void rope_apply(float* __restrict__ qb, float* __restrict__ kb,
                           const float* __restrict__ cs,
                           const float* __restrict__ sn) {
  int id = blockIdx.x * 256 + threadIdx.x;  // < 2 * H*T*32
  const int n = HH * TT * 32;               // 1,048,576
  int which = id >= n;
  int i = which ? id - n : id;
  float* p = which ? kb : qb;
  int h = i >> 16;
  int rem = i & 65535;
  size_t off = ((size_t)h * TT) * DH + (rem >> 5) * DH + (rem & 31);
  float c = cs[rem];
  float s = sn[rem];
  float a = p[off];
  float b = p[off + 32];
  p[off] = a * c - b * s;
  p[off + 32] = b * c + a * s;
}

// ---------------------------------------------------------------------------
// Tiled flash attention, fp32 (unchanged from round 4's measured kernel).
// ---------------------------------------------------------------------------
__global__ __launch_bounds__(256) void attn_tile(
    const float* __restrict__ Q, const float* __restrict__ K,
    const float* __restrict__ V, float* __restrict__ O) {
  __shared__ __attribute__((aligned(16))) float Qs[64][68];  // [d][q], prescaled
  __shared__ __attribute__((aligned(16))) float Ks[64][68];  // [d][k]
  __shared__ __attribute__((aligned(16))) float Ps[64][68];  // [k][q]
  __shared__ __attribute__((aligned(16))) float Vs[64][72];  // [k][d]

  const int tid = threadIdx.x;
  const int tx = tid & 15;
  const int ty = tid >> 4;
  const int r = tid >> 2;
  const int c = tid & 3;
  const int h = blockIdx.x & 15;
  const int idx = blockIdx.x >> 4;
  const int tile = (idx < 16) ? idx : 47 - idx;
  const int qbase = tile << 6;
  const int nc = tile + 1;

  const float* Qh = Q + (size_t)h * TT * DH;
  const float* Kh = K + (size_t)h * TT * DH;
  const float* Vh = V + (size_t)h * TT * DH;

#pragma unroll
  for (int p = 0; p < 4; p++) {
    const int d0 = p * 16 + c * 4;
    float4 q4 = *(const float4*)&Qh[(size_t)(qbase + r) * DH + d0];
    Qs[d0 + 0][r] = q4.x * 0.125f;
    Qs[d0 + 1][r] = q4.y * 0.125f;
    Qs[d0 + 2][r] = q4.z * 0.125f;
    Qs[d0 + 3][r] = q4.w * 0.125f;
  }

  float m[4], l[4], oacc[4][4];
#pragma unroll
  for (int i = 0; i < 4; i++) {
    m[i] = -1e30f;
    l[i] = 0.f;
#pragma unroll
    for (int j = 0; j < 4; j++) oacc[i][j] = 0.f;
  }

  float4 kst[4], vst[4];
#pragma unroll
  for (int p = 0; p < 4; p++) {
    const int d0 = p * 16 + c * 4;
    kst[p] = *(const float4*)&Kh[(size_t)r * DH + d0];
    vst[p] = *(const float4*)&Vh[(size_t)r * DH + d0];
  }

  for (int ch = 0; ch < nc; ch++) {
    __syncthreads();
#pragma unroll
    for (int p = 0; p < 4; p++) {
      const int d0 = p * 16 + c * 4;
      Ks[d0 + 0][r] = kst[p].x;
      Ks[d0 + 1][r] = kst[p].y;
      Ks[d0 + 2][r] = kst[p].z;
      Ks[d0 + 3][r] = kst[p].w;
      *(float4*)&Vs[r][d0] = vst[p];
    }
    __syncthreads();
    {
      const int nb = ((ch + 1 < nc) ? ch + 1 : ch) << 6;
#pragma unroll
      for (int p = 0; p < 4; p++) {
        const int d0 = p * 16 + c * 4;
        kst[p] = *(const float4*)&Kh[(size_t)(nb + r) * DH + d0];
        vst[p] = *(const float4*)&Vh[(size_t)(nb + r) * DH + d0];
      }
    }
    float sc[4][4];
#pragma unroll
    for (int i = 0; i < 4; i++)
#pragma unroll
      for (int j = 0; j < 4; j++) sc[i][j] = 0.f;
#pragma unroll 8
    for (int kk = 0; kk < 64; kk++) {
      float4 qv = *(const float4*)&Qs[kk][ty * 4];
      float4 kv = *(const float4*)&Ks[kk][tx * 4];
      sc[0][0] = fmaf(qv.x, kv.x, sc[0][0]);
      sc[0][1] = fmaf(qv.x, kv.y, sc[0][1]);
      sc[0][2] = fmaf(qv.x, kv.z, sc[0][2]);
      sc[0][3] = fmaf(qv.x, kv.w, sc[0][3]);
      sc[1][0] = fmaf(qv.y, kv.x, sc[1][0]);
      sc[1][1] = fmaf(qv.y, kv.y, sc[1][1]);
      sc[1][2] = fmaf(qv.y, kv.z, sc[1][2]);
      sc[1][3] = fmaf(qv.y, kv.w, sc[1][3]);
      sc[2][0] = fmaf(qv.z, kv.x, sc[2][0]);
      sc[2][1] = fmaf(qv.z, kv.y, sc[2][1]);
      sc[2][2] = fmaf(qv.z, kv.z, sc[2][2]);
      sc[2][3] = fmaf(qv.z, kv.w, sc[2][3]);
      sc[3][0] = fmaf(qv.w, kv.x, sc[3][0]);
      sc[3][1] = fmaf(qv.w, kv.y, sc[3][1]);
      sc[3][2] = fmaf(qv.w, kv.z, sc[3][2]);
      sc[3][3] = fmaf(qv.w, kv.w, sc[3][3]);
    }
    if (ch == tile) {
#pragma unroll
      for (int i = 0; i < 4; i++)
#pragma unroll
        for (int j = 0; j < 4; j++)
          if (tx * 4 + j > ty * 4 + i) sc[i][j] = -1e30f;
    }
    float pr[4][4];
#pragma unroll
    for (int i = 0; i < 4; i++) {
      float rm = fmaxf(fmaxf(sc[i][0], sc[i][1]), fmaxf(sc[i][2], sc[i][3]));
      rm = fmaxf(rm, __shfl_xor(rm, 1));
      rm = fmaxf(rm, __shfl_xor(rm, 2));
      rm = fmaxf(rm, __shfl_xor(rm, 4));
      rm = fmaxf(rm, __shfl_xor(rm, 8));
      const float mn = fmaxf(m[i], rm);
      const float corr = __expf(m[i] - mn);
      float rs = 0.f;
#pragma unroll
      for (int j = 0; j < 4; j++) {
        pr[i][j] = __expf(sc[i][j] - mn);
        rs += pr[i][j];
      }
      rs += __shfl_xor(rs, 1);
      rs += __shfl_xor(rs, 2);
      rs += __shfl_xor(rs, 4);
      rs += __shfl_xor(rs, 8);
      l[i] = l[i] * corr + rs;
      m[i] = mn;
      oacc[i][0] *= corr;
      oacc[i][1] *= corr;
      oacc[i][2] *= corr;
      oacc[i][3] *= corr;
    }
#pragma unroll
    for (int i = 0; i < 4; i++)
#pragma unroll
      for (int j = 0; j < 4; j++) Ps[tx * 4 + j][ty * 4 + i] = pr[i][j];
    __syncthreads();
#pragma unroll 8
    for (int kk = 0; kk < 64; kk++) {
      float4 pv = *(const float4*)&Ps[kk][ty * 4];
      float4 vv = *(const float4*)&Vs[kk][tx * 4];
      oacc[0][0] = fmaf(pv.x, vv.x, oacc[0][0]);
      oacc[0][1] = fmaf(pv.x, vv.y, oacc[0][1]);
      oacc[0][2] = fmaf(pv.x, vv.z, oacc[0][2]);
      oacc[0][3] = fmaf(pv.x, vv.w, oacc[0][3]);
      oacc[1][0] = fmaf(pv.y, vv.x, oacc[1][0]);
      oacc[1][1] = fmaf(pv.y, vv.y, oacc[1][1]);
      oacc[1][2] = fmaf(pv.y, vv.z, oacc[1][2]);
      oacc[1][3] = fmaf(pv.y, vv.w, oacc[1][3]);
      oacc[2][0] = fmaf(pv.z, vv.x, oacc[2][0]);
      oacc[2][1] = fmaf(pv.z, vv.y, oacc[2][1]);
      oacc[2][2] = fmaf(pv.z, vv.z, oacc[2][2]);
      oacc[2][3] = fmaf(pv.z, vv.w, oacc[2][3]);
      oacc[3][0] = fmaf(pv.w, vv.x, oacc[3][0]);
      oacc[3][1] = fmaf(pv.w, vv.y, oacc[3][1]);
      oacc[3][2] = fmaf(pv.w, vv.z, oacc[3][2]);
      oacc[3][3] = fmaf(pv.w, vv.w, oacc[3][3]);
    }
  }
#pragma unroll
  for (int i = 0; i < 4; i++) {
    const float inv = 1.f / l[i];
    float4 o4 = make_float4(oacc[i][0] * inv, oacc[i][1] * inv,
                            oacc[i][2] * inv, oacc[i][3] * inv);
    *(float4*)&O[(size_t)(qbase + ty * 4 + i) * EE + h * DH + tx * 4] = o4;
  }
}

// ---------------------------------------------------------------------------
extern "C" void kernel_launch(void* const* d_in, const int* in_sizes, int n_in,
                              void* d_out, int out_size, void* d_ws,
                              size_t ws_size, hipStream_t stream) {
  const float* x = (const float*)d_in[0];    // [2048][1024]
  const float* W1 = (const float*)d_in[1];   // [3072][1024]
  const float* W2 = (const float*)d_in[2];   // [1024][1024]
  float* out = (float*)d_out;                // [2048][1024]

  float* ws = (float*)d_ws;
  const size_t HTD = (size_t)HH * TT * DH;   // 2,097,152
  float* qb = ws;
  float* kb = qb + HTD;
  float* vb = kb + HTD;
  float* ob = vb + HTD;                      // [T][E] fp32
  float* cs = ob + (size_t)TT * EE;
  float* sn = cs + (size_t)TT * 32;
  u16* xb = (u16*)(sn + (size_t)TT * 32);    // bf16 copies
  u16* w1b = xb + (size_t)TT * EE;
  u16* w2b = w1b + (size_t)3 * EE * EE;
  u16* obb = w2b + (size_t)EE * EE;

  const int n8x = TT * EE / 8, n8w1 = 3 * EE * EE / 8, n8w2 = EE * EE / 8;
  cvt_bf16<<<(n8x + 255) / 256, 256, 0, stream>>>(x, xb, n8x);
  cvt_bf16<<<(n8w1 + 255) / 256, 256, 0, stream>>>(W1, w1b, n8w1);
  cvt_bf16<<<(n8w2 + 255) / 256, 256, 0, stream>>>(W2, w2b, n8w2);
  rope_table<<<(TT * 32) / 256, 256, 0, stream>>>(cs, sn);
  // QKV: [2048 x 3072] = x @ W1^T  (scatter into q/k/v)
  gemm_mfma<1><<<dim3(3 * EE / 128, TT / 128), 256, 0, stream>>>(
      xb, w1b, nullptr, qb, kb, vb, TT, 3 * EE, EE);
  rope_apply<<<(2 * HH * TT * 32) / 256, 256, 0, stream>>>(qb, kb, cs, sn);
  attn_tile<<<512, 256, 0, stream>>>(qb, kb, vb, ob);
  cvt_bf16<<<(n8x + 255) / 256, 256, 0, stream>>>(ob, obb, n8x);
  // proj: [2048 x 1024] = ob @ W2^T
  gemm_mfma<0><<<dim3(EE / 128, TT / 128), 256, 0, stream>>>(
      obb, w2b, out, nullptr, nullptr, nullptr, TT, EE, EE);
}

// Round 10
// 205.583 us; speedup vs baseline: 9.1176x; 1.7618x over previous
//
#include <hip/hip_runtime.h>
#include <math.h>

// Problem constants
#define TT 2048
#define EE 1024
#define HH 16
#define DH 64

typedef unsigned short u16;
typedef __attribute__((ext_vector_type(8))) short bf16x8;   // 8 bf16 = 4 VGPRs
typedef __attribute__((ext_vector_type(4))) float f32x4;
typedef __attribute__((address_space(1))) unsigned int uint_g;
typedef __attribute__((address_space(3))) unsigned int uint_l;

// fp32 -> bf16 round-to-nearest-even
__device__ __forceinline__ u16 f2bf(float f) {
  unsigned u = __float_as_uint(f);
  u += 0x7fffu + ((u >> 16) & 1u);
  return (u16)(u >> 16);
}

// ---------------------------------------------------------------------------
// fp32 -> bf16 conversion, 8 elements/thread (n8 = n/8)
// ---------------------------------------------------------------------------
__global__ __launch_bounds__(256) void cvt_bf16(const float* __restrict__ s,
                                                u16* __restrict__ d, int n8) {
  int i = blockIdx.x * 256 + threadIdx.x;
  if (i >= n8) return;
  const float4* s4 = (const float4*)s;
  float4 a = s4[2 * i], b = s4[2 * i + 1];
  bf16x8 o;
  o[0] = (short)f2bf(a.x); o[1] = (short)f2bf(a.y);
  o[2] = (short)f2bf(a.z); o[3] = (short)f2bf(a.w);
  o[4] = (short)f2bf(b.x); o[5] = (short)f2bf(b.y);
  o[6] = (short)f2bf(b.z); o[7] = (short)f2bf(b.w);
  *(bf16x8*)&d[8 * i] = o;
}

// ---------------------------------------------------------------------------
// bf16 MFMA GEMM (TN): C[m][n] = sum_k A[m][k] * B[n][k], fp32 accum.
// 128x128 tile, BK=32, 256 threads = 4 waves (2x2), 4x4 16x16x32 frags/wave.
// EPI==0: row-major fp32 C.
// EPI==1: q,k -> fp32 [H][T][DH] (rope still to come); v -> bf16 [H][DH][T].
// ---------------------------------------------------------------------------
template <int EPI>
__global__ __launch_bounds__(256) void gemm_mfma(
    const u16* __restrict__ A, const u16* __restrict__ B, float* __restrict__ C,
    float* __restrict__ qb, float* __restrict__ kb, u16* __restrict__ vt,
    int M, int N, int K) {
  __shared__ u16 smem[8192];  // As[128][32] @0 | Bs[128][32] @4096 (ushorts)
  const int tid = threadIdx.x;
  const int lane = tid & 63;
  const int wid = tid >> 6;
  const int wr = wid >> 1, wc = wid & 1;
  const int m0 = blockIdx.y * 128, n0 = blockIdx.x * 128;

  const u16* gp[4];
  int lo[4];
#pragma unroll
  for (int q = 0; q < 4; q++) {
    int o = (wid * 4 + q) * 1024 + lane * 16;  // byte offset into smem
    lo[q] = o >> 1;
    if (o < 8192) {
      int row = o >> 6, col = (o >> 1) & 31;
      gp[q] = A + (size_t)(m0 + row) * K + col;
    } else {
      int o2 = o - 8192;
      int row = o2 >> 6, col = (o2 >> 1) & 31;
      gp[q] = B + (size_t)(n0 + row) * K + col;
    }
  }

  const int a_off = (wr * 64 + (lane & 15)) * 32 + (lane >> 4) * 8;
  const int b_off = 4096 + (wc * 64 + (lane & 15)) * 32 + (lane >> 4) * 8;

  f32x4 acc[4][4];
#pragma unroll
  for (int i = 0; i < 4; i++)
#pragma unroll
    for (int j = 0; j < 4; j++) acc[i][j] = f32x4{0.f, 0.f, 0.f, 0.f};

  for (int k0 = 0; k0 < K; k0 += 32) {
    __syncthreads();
#pragma unroll
    for (int q = 0; q < 4; q++) {
      __builtin_amdgcn_global_load_lds((const uint_g*)gp[q],
                                       (uint_l*)&smem[lo[q]], 16, 0, 0);
      gp[q] += 32;
    }
    __syncthreads();
    bf16x8 af[4], bg[4];
#pragma unroll
    for (int i = 0; i < 4; i++) af[i] = *(const bf16x8*)&smem[a_off + i * 512];
#pragma unroll
    for (int j = 0; j < 4; j++) bg[j] = *(const bf16x8*)&smem[b_off + j * 512];
#pragma unroll
    for (int i = 0; i < 4; i++)
#pragma unroll
      for (int j = 0; j < 4; j++)
        acc[i][j] = __builtin_amdgcn_mfma_f32_16x16x32_bf16(af[i], bg[j],
                                                            acc[i][j], 0, 0, 0);
  }

  // epilogue: C/D layout col(n)=lane&15, row(m)=(lane>>4)*4+reg
  const int rbase = (lane >> 4) * 4;
  const int ncol = lane & 15;
  if (EPI == 0) {
#pragma unroll
    for (int i = 0; i < 4; i++) {
      int m = m0 + wr * 64 + i * 16 + rbase;
#pragma unroll
      for (int j = 0; j < 4; j++) {
        int n = n0 + wc * 64 + j * 16 + ncol;
#pragma unroll
        for (int r = 0; r < 4; r++) C[(size_t)(m + r) * N + n] = acc[i][j][r];
      }
    }
  } else {
#pragma unroll
    for (int j = 0; j < 4; j++) {
      int n = n0 + wc * 64 + j * 16 + ncol;
      int which = n >> 10, h = (n >> 6) & 15, d = n & 63;
#pragma unroll
      for (int i = 0; i < 4; i++) {
        int m = m0 + wr * 64 + i * 16 + rbase;
        if (which == 2) {
          // v: transposed bf16 [H][DH][T]
#pragma unroll
          for (int r = 0; r < 4; r++)
            vt[((size_t)h * DH + d) * TT + m + r] = f2bf(acc[i][j][r]);
        } else {
          float* dst = (which == 0) ? qb : kb;
#pragma unroll
          for (int r = 0; r < 4; r++)
            dst[((size_t)h * TT + m + r) * DH + d] = acc[i][j][r];
        }
      }
    }
  }
}

// ---------------------------------------------------------------------------
// RoPE cos/sin table: [T][32].
// ---------------------------------------------------------------------------
__global__ void rope_table(float* __restrict__ cs, float* __restrict__ sn) {
  int i = blockIdx.x * 256 + threadIdx.x;  // < 2048*32
  int t = i >> 5;
  int d = i & 31;
  float inv = powf(10000.f, -((float)d) / 32.f);
  float ang = (float)t * inv;
  cs[i] = (float)cos((double)ang);
  sn[i] = (float)sin((double)ang);
}

// ---------------------------------------------------------------------------
// RoPE on fp32 q/k ([H][T][DH]) -> bf16 q/k.  Pairs (d, d+32), d<32.
// ---------------------------------------------------------------------------
__global__ void rope_apply_bf16(const float* __restrict__ qb,
                                const float* __restrict__ kb,
                                u16* __restrict__ q16, u16* __restrict__ k16,
                                const float* __restrict__ cs,
                                const float* __restrict__ sn) {
  int id = blockIdx.x * 256 + threadIdx.x;  // < 2 * H*T*32
  const int n = HH * TT * 32;               // 1,048,576
  int which = id >= n;
  int i = which ? id - n : id;
  const float* p = which ? kb : qb;
  u16* dst = which ? k16 : q16;
  int h = i >> 16;
  int rem = i & 65535;
  size_t off = ((size_t)h * TT) * DH + (size_t)(rem >> 5) * DH + (rem & 31);
  float c = cs[rem];
  float s = sn[rem];
  float a = p[off];
  float b = p[off + 32];
  dst[off] = f2bf(a * c - b * s);
  dst[off + 32] = f2bf(b * c + a * s);
}

// ---------------------------------------------------------------------------
// bf16 MFMA flash attention.  Block = 64 q-rows (4 waves x 16 rows, fully
// independent; no __syncthreads).  K-chunks of 64 keys.
// QK^T: A = Q frags (regs), B = K direct from global ([T][64] bf16 matches
// B-frag layout).  PV: A = P via per-wave LDS slice, B = Vt direct from
// global ([DH][T] bf16).  Softmax fp32, O accum fp32, output bf16 [T][E].
// ---------------------------------------------------------------------------
__global__ __launch_bounds__(256) void attn_mfma(
    const u16* __restrict__ Q, const u16* __restrict__ K,
    const u16* __restrict__ Vt, u16* __restrict__ O) {
  __shared__ u16 P_lds[64][72];  // [q-row within block][key], +8 pad
  const int tid = threadIdx.x;
  const int lane = tid & 63;
  const int wid = tid >> 6;
  const int l15 = lane & 15;
  const int l4 = lane >> 4;       // 0..3
  const int rbase = l4 * 4;       // C-layout row base
  const int h = blockIdx.x & 15;
  const int idx = blockIdx.x >> 4;
  const int tile = (idx < 16) ? idx : 47 - idx;  // pair heavy+light
  const int qbase = tile << 6;
  const int nc = tile + 1;

  const u16* Qh = Q + (size_t)h * TT * DH;
  const u16* Kh = K + (size_t)h * TT * DH;
  const u16* Vh = Vt + (size_t)h * DH * TT;

  // Q A-frags in registers (2 k-steps over dh); row = lane&15
  const int qrow = qbase + wid * 16 + l15;
  bf16x8 qf0 = *(const bf16x8*)&Qh[(size_t)qrow * DH + l4 * 8];
  bf16x8 qf1 = *(const bf16x8*)&Qh[(size_t)qrow * DH + 32 + l4 * 8];

  float m[4], l[4];
  f32x4 oacc[4];
#pragma unroll
  for (int r = 0; r < 4; r++) {
    m[r] = -1e30f;
    l[r] = 0.f;
  }
#pragma unroll
  for (int j = 0; j < 4; j++) oacc[j] = f32x4{0.f, 0.f, 0.f, 0.f};

  for (int ch = 0; ch < nc; ch++) {
    const int kbase = ch << 6;
    // ---- QK^T: S[16 q][64 keys], 8 MFMAs ----
    f32x4 s[4];
#pragma unroll
    for (int j = 0; j < 4; j++) s[j] = f32x4{0.f, 0.f, 0.f, 0.f};
#pragma unroll
    for (int j = 0; j < 4; j++) {
      bf16x8 kf0 =
          *(const bf16x8*)&Kh[(size_t)(kbase + j * 16 + l15) * DH + l4 * 8];
      bf16x8 kf1 = *(const bf16x8*)&Kh[(size_t)(kbase + j * 16 + l15) * DH +
                                       32 + l4 * 8];
      s[j] = __builtin_amdgcn_mfma_f32_16x16x32_bf16(qf0, kf0, s[j], 0, 0, 0);
      s[j] = __builtin_amdgcn_mfma_f32_16x16x32_bf16(qf1, kf1, s[j], 0, 0, 0);
    }
    // scale + causal mask (diagonal chunk only)
#pragma unroll
    for (int j = 0; j < 4; j++) {
      s[j][0] *= 0.125f; s[j][1] *= 0.125f;
      s[j][2] *= 0.125f; s[j][3] *= 0.125f;
    }
    if (ch == tile) {
#pragma unroll
      for (int j = 0; j < 4; j++) {
        int kg = kbase + j * 16 + l15;
#pragma unroll
        for (int r = 0; r < 4; r++) {
          int qg = qbase + wid * 16 + rbase + r;
          if (kg > qg) s[j][r] = -1e30f;
        }
      }
    }
    // ---- online softmax per row (16-lane groups share rows) ----
#pragma unroll
    for (int r = 0; r < 4; r++) {
      float rm = fmaxf(fmaxf(s[0][r], s[1][r]), fmaxf(s[2][r], s[3][r]));
      rm = fmaxf(rm, __shfl_xor(rm, 1));
      rm = fmaxf(rm, __shfl_xor(rm, 2));
      rm = fmaxf(rm, __shfl_xor(rm, 4));
      rm = fmaxf(rm, __shfl_xor(rm, 8));
      const float mn = fmaxf(m[r], rm);
      const float corr = __expf(m[r] - mn);
      m[r] = mn;
      float rs = 0.f;
#pragma unroll
      for (int j = 0; j < 4; j++) {
        float p = __expf(s[j][r] - mn);
        s[j][r] = p;
        rs += p;
      }
      rs += __shfl_xor(rs, 1);
      rs += __shfl_xor(rs, 2);
      rs += __shfl_xor(rs, 4);
      rs += __shfl_xor(rs, 8);
      l[r] = l[r] * corr + rs;
      oacc[0][r] *= corr;
      oacc[1][r] *= corr;
      oacc[2][r] *= corr;
      oacc[3][r] *= corr;
    }
    // ---- P (bf16) to own-wave LDS slice; no barrier needed ----
    const int prow0 = wid * 16 + rbase;
#pragma unroll
    for (int j = 0; j < 4; j++)
#pragma unroll
      for (int r = 0; r < 4; r++)
        P_lds[prow0 + r][j * 16 + l15] = f2bf(s[j][r]);
    // ---- PV: O[16 q][64 dh] += P @ V, 8 MFMAs ----
#pragma unroll
    for (int ks = 0; ks < 2; ks++) {
      bf16x8 pa = *(const bf16x8*)&P_lds[wid * 16 + l15][ks * 32 + l4 * 8];
#pragma unroll
      for (int j = 0; j < 4; j++) {
        bf16x8 vf = *(const bf16x8*)&Vh[(size_t)(j * 16 + l15) * TT + kbase +
                                        ks * 32 + l4 * 8];
        oacc[j] =
            __builtin_amdgcn_mfma_f32_16x16x32_bf16(pa, vf, oacc[j], 0, 0, 0);
      }
    }
  }
  // ---- epilogue: divide by l, write bf16 [T][E] ----
#pragma unroll
  for (int r = 0; r < 4; r++) {
    const float inv = 1.f / l[r];
    const int qg = qbase + wid * 16 + rbase + r;
#pragma unroll
    for (int j = 0; j < 4; j++)
      O[(size_t)qg * EE + h * DH + j * 16 + l15] = f2bf(oacc[j][r] * inv);
  }
}

// ---------------------------------------------------------------------------
extern "C" void kernel_launch(void* const* d_in, const int* in_sizes, int n_in,
                              void* d_out, int out_size, void* d_ws,
                              size_t ws_size, hipStream_t stream) {
  const float* x = (const float*)d_in[0];    // [2048][1024]
  const float* W1 = (const float*)d_in[1];   // [3072][1024]
  const float* W2 = (const float*)d_in[2];   // [1024][1024]
  float* out = (float*)d_out;                // [2048][1024]

  float* ws = (float*)d_ws;
  const size_t HTD = (size_t)HH * TT * DH;   // 2,097,152
  float* qb = ws;                            // fp32 q (pre-rope)
  float* kb = qb + HTD;                      // fp32 k (pre-rope)
  float* cs = kb + HTD;
  float* sn = cs + (size_t)TT * 32;
  u16* qb16 = (u16*)(sn + (size_t)TT * 32);  // bf16 roped q [H][T][DH]
  u16* kb16 = qb16 + HTD;                    // bf16 roped k
  u16* vt16 = kb16 + HTD;                    // bf16 v transposed [H][DH][T]
  u16* obb = vt16 + HTD;                     // bf16 attn out [T][E]
  u16* xb = obb + (size_t)TT * EE;           // bf16 inputs
  u16* w1b = xb + (size_t)TT * EE;
  u16* w2b = w1b + (size_t)3 * EE * EE;

  const int n8x = TT * EE / 8, n8w1 = 3 * EE * EE / 8, n8w2 = EE * EE / 8;
  cvt_bf16<<<(n8x + 255) / 256, 256, 0, stream>>>(x, xb, n8x);
  cvt_bf16<<<(n8w1 + 255) / 256, 256, 0, stream>>>(W1, w1b, n8w1);
  cvt_bf16<<<(n8w2 + 255) / 256, 256, 0, stream>>>(W2, w2b, n8w2);
  rope_table<<<(TT * 32) / 256, 256, 0, stream>>>(cs, sn);
  // QKV: [2048 x 3072] = x @ W1^T;  q,k fp32; v bf16 transposed
  gemm_mfma<1><<<dim3(3 * EE / 128, TT / 128), 256, 0, stream>>>(
      xb, w1b, nullptr, qb, kb, vt16, TT, 3 * EE, EE);
  rope_apply_bf16<<<(2 * HH * TT * 32) / 256, 256, 0, stream>>>(
      qb, kb, qb16, kb16, cs, sn);
  attn_mfma<<<512, 256, 0, stream>>>(qb16, kb16, vt16, obb);
  // proj: [2048 x 1024] = attn @ W2^T
  gemm_mfma<0><<<dim3(EE / 128, TT / 128), 256, 0, stream>>>(
      obb, w2b, out, nullptr, nullptr, nullptr, TT, EE, EE);
}

// Round 12
// 201.908 us; speedup vs baseline: 9.2836x; 1.0182x over previous
//
#include <hip/hip_runtime.h>
#include <math.h>

// Problem constants
#define TT 2048
#define EE 1024
#define HH 16
#define DH 64

typedef unsigned short u16;
typedef __attribute__((ext_vector_type(8))) short bf16x8;   // 8 bf16 = 4 VGPRs
typedef __attribute__((ext_vector_type(4))) float f32x4;
typedef __attribute__((address_space(1))) unsigned int uint_g;
typedef __attribute__((address_space(3))) unsigned int uint_l;

// fp32 -> bf16 round-to-nearest-even
__device__ __forceinline__ u16 f2bf(float f) {
  unsigned u = __float_as_uint(f);
  u += 0x7fffu + ((u >> 16) & 1u);
  return (u16)(u >> 16);
}

// ---------------------------------------------------------------------------
// Fused fp32 -> bf16 conversion of x, W1, W2 (one launch).
// Region sizes in n8 units (n/8): x 262144, W1 393216, W2 131072.
// ---------------------------------------------------------------------------
__global__ __launch_bounds__(256) void cvt_all(
    const float* __restrict__ x, const float* __restrict__ W1,
    const float* __restrict__ W2, u16* __restrict__ xb, u16* __restrict__ w1b,
    u16* __restrict__ w2b) {
  int i = blockIdx.x * 256 + threadIdx.x;  // < 786432
  const float* s;
  u16* d;
  if (i < 262144) {
    s = x; d = xb;
  } else if (i < 262144 + 393216) {
    i -= 262144; s = W1; d = w1b;
  } else {
    i -= 262144 + 393216; s = W2; d = w2b;
  }
  const float4* s4 = (const float4*)s;
  float4 a = s4[2 * i], b = s4[2 * i + 1];
  bf16x8 o;
  o[0] = (short)f2bf(a.x); o[1] = (short)f2bf(a.y);
  o[2] = (short)f2bf(a.z); o[3] = (short)f2bf(a.w);
  o[4] = (short)f2bf(b.x); o[5] = (short)f2bf(b.y);
  o[6] = (short)f2bf(b.z); o[7] = (short)f2bf(b.w);
  *(bf16x8*)&d[8 * i] = o;
}

// ---------------------------------------------------------------------------
// RoPE cos/sin table: [T][32].
// ---------------------------------------------------------------------------
__global__ void rope_table(float* __restrict__ cs, float* __restrict__ sn) {
  int i = blockIdx.x * 256 + threadIdx.x;  // < 2048*32
  int t = i >> 5;
  int d = i & 31;
  float inv = powf(10000.f, -((float)d) / 32.f);
  float ang = (float)t * inv;
  cs[i] = (float)cos((double)ang);
  sn[i] = (float)sin((double)ang);
}

// ---------------------------------------------------------------------------
// bf16 MFMA GEMM (TN): C[m][n] = sum_k A[m][k] * B[n][k], fp32 accum.
// 128x128 tile, BK=32, 256 threads = 4 waves (2x2), 4x4 16x16x32 frags/wave.
// EPI==0: row-major fp32 C.
// EPI==1: QKV epilogue — each block is wholly in q, k, or v (n0 % 1024 has
//   uniform n>>10).  q,k: RoPE applied in-register (pair (j, j+2) = (d,d+32))
//   and written bf16 [H][T][DH].  v: bf16 transposed [H][DH][T].
// ---------------------------------------------------------------------------
template <int EPI>
__global__ __launch_bounds__(256) void gemm_mfma(
    const u16* __restrict__ A, const u16* __restrict__ B, float* __restrict__ C,
    u16* __restrict__ q16, u16* __restrict__ k16, u16* __restrict__ vt,
    const float* __restrict__ cs, const float* __restrict__ sn, int M, int N,
    int K) {
  __shared__ u16 smem[8192];  // As[128][32] @0 | Bs[128][32] @4096 (ushorts)
  const int tid = threadIdx.x;
  const int lane = tid & 63;
  const int wid = tid >> 6;
  const int wr = wid >> 1, wc = wid & 1;
  const int m0 = blockIdx.y * 128, n0 = blockIdx.x * 128;

  const u16* gp[4];
  int lo[4];
#pragma unroll
  for (int q = 0; q < 4; q++) {
    int o = (wid * 4 + q) * 1024 + lane * 16;  // byte offset into smem
    lo[q] = o >> 1;
    if (o < 8192) {
      int row = o >> 6, col = (o >> 1) & 31;
      gp[q] = A + (size_t)(m0 + row) * K + col;
    } else {
      int o2 = o - 8192;
      int row = o2 >> 6, col = (o2 >> 1) & 31;
      gp[q] = B + (size_t)(n0 + row) * K + col;
    }
  }

  const int a_off = (wr * 64 + (lane & 15)) * 32 + (lane >> 4) * 8;
  const int b_off = 4096 + (wc * 64 + (lane & 15)) * 32 + (lane >> 4) * 8;

  f32x4 acc[4][4];
#pragma unroll
  for (int i = 0; i < 4; i++)
#pragma unroll
    for (int j = 0; j < 4; j++) acc[i][j] = f32x4{0.f, 0.f, 0.f, 0.f};

  for (int k0 = 0; k0 < K; k0 += 32) {
    __syncthreads();
#pragma unroll
    for (int q = 0; q < 4; q++) {
      __builtin_amdgcn_global_load_lds((const uint_g*)gp[q],
                                       (uint_l*)&smem[lo[q]], 16, 0, 0);
      gp[q] += 32;
    }
    __syncthreads();
    bf16x8 af[4], bg[4];
#pragma unroll
    for (int i = 0; i < 4; i++) af[i] = *(const bf16x8*)&smem[a_off + i * 512];
#pragma unroll
    for (int j = 0; j < 4; j++) bg[j] = *(const bf16x8*)&smem[b_off + j * 512];
#pragma unroll
    for (int i = 0; i < 4; i++)
#pragma unroll
      for (int j = 0; j < 4; j++)
        acc[i][j] = __builtin_amdgcn_mfma_f32_16x16x32_bf16(af[i], bg[j],
                                                            acc[i][j], 0, 0, 0);
  }

  // epilogue: C/D layout col(n)=lane&15, row(m)=(lane>>4)*4+reg
  const int rbase = (lane >> 4) * 4;
  const int ncol = lane & 15;
  if (EPI == 0) {
#pragma unroll
    for (int i = 0; i < 4; i++) {
      int m = m0 + wr * 64 + i * 16 + rbase;
#pragma unroll
      for (int j = 0; j < 4; j++) {
        int n = n0 + wc * 64 + j * 16 + ncol;
#pragma unroll
        for (int r = 0; r < 4; r++) C[(size_t)(m + r) * N + n] = acc[i][j][r];
      }
    }
  } else {
    const int which = n0 >> 10;  // uniform per block
    if (which == 2) {
      // v: transposed bf16 [H][DH][T]
#pragma unroll
      for (int j = 0; j < 4; j++) {
        int n = n0 + wc * 64 + j * 16 + ncol;
        int h = (n >> 6) & 15, d = n & 63;
#pragma unroll
        for (int i = 0; i < 4; i++) {
          int m = m0 + wr * 64 + i * 16 + rbase;
#pragma unroll
          for (int r = 0; r < 4; r++)
            vt[((size_t)h * DH + d) * TT + m + r] = f2bf(acc[i][j][r]);
        }
      }
    } else {
      // q,k: fused RoPE (pairs (j, j+2) hold dims (d, d+32), d<32), bf16 out
      u16* dst = (which == 0) ? q16 : k16;
#pragma unroll
      for (int j = 0; j < 2; j++) {
        int n = n0 + wc * 64 + j * 16 + ncol;
        int h = (n >> 6) & 15, d = n & 63;  // d < 32
#pragma unroll
        for (int i = 0; i < 4; i++) {
          int mrow = m0 + wr * 64 + i * 16 + rbase;
#pragma unroll
          for (int r = 0; r < 4; r++) {
            int t = mrow + r;
            float c = cs[t * 32 + d];
            float s = sn[t * 32 + d];
            float a = acc[i][j][r];
            float b = acc[i][j + 2][r];
            size_t off = ((size_t)h * TT + t) * DH + d;
            dst[off] = f2bf(a * c - b * s);
            dst[off + 32] = f2bf(b * c + a * s);
          }
        }
      }
    }
  }
}

// ---------------------------------------------------------------------------
// bf16 MFMA flash attention.  One wave (64 thr) per block = 16 q-rows.
// Grid 2048 = 16 heads x 128 tiles, heavy tiles dispatched first.
// QK^T: A = Q frags (regs), B = K direct from global ([T][64] bf16 = B-frag
// layout).  PV: A = P via per-block LDS re-layout, B = Vt direct from global
// ([DH][T] bf16).  Softmax fp32; O accum fp32; output bf16 [T][E].
// No __syncthreads anywhere.
// ---------------------------------------------------------------------------
__global__ __launch_bounds__(64) void attn_mfma(
    const u16* __restrict__ Q, const u16* __restrict__ K,
    const u16* __restrict__ Vt, u16* __restrict__ O) {
  __shared__ u16 P_lds[16][72];  // [q-row][key], +8 pad
  const int lane = threadIdx.x;
  const int l15 = lane & 15;
  const int l4 = lane >> 4;       // 0..3
  const int rbase = l4 * 4;       // C-layout row base
  const int h = blockIdx.x & 15;
  const int tile = 127 - (blockIdx.x >> 4);  // heavy first
  const int qbase = tile << 4;
  const int nc = ((qbase + 15) >> 6) + 1;

  const u16* Qh = Q + (size_t)h * TT * DH;
  const u16* Kh = K + (size_t)h * TT * DH;
  const u16* Vh = Vt + (size_t)h * DH * TT;

  // Q A-frags in registers (2 k-steps over dh); row = lane&15
  const int qrow = qbase + l15;
  bf16x8 qf0 = *(const bf16x8*)&Qh[(size_t)qrow * DH + l4 * 8];
  bf16x8 qf1 = *(const bf16x8*)&Qh[(size_t)qrow * DH + 32 + l4 * 8];

  float m[4], l[4];
  f32x4 oacc[4];
#pragma unroll
  for (int r = 0; r < 4; r++) {
    m[r] = -1e30f;
    l[r] = 0.f;
  }
#pragma unroll
  for (int j = 0; j < 4; j++) oacc[j] = f32x4{0.f, 0.f, 0.f, 0.f};

  for (int ch = 0; ch < nc; ch++) {
    const int kbase = ch << 6;
    // ---- QK^T: S[16 q][64 keys], 8 MFMAs ----
    f32x4 s[4];
#pragma unroll
    for (int j = 0; j < 4; j++) s[j] = f32x4{0.f, 0.f, 0.f, 0.f};
#pragma unroll
    for (int j = 0; j < 4; j++) {
      bf16x8 kf0 =
          *(const bf16x8*)&Kh[(size_t)(kbase + j * 16 + l15) * DH + l4 * 8];
      bf16x8 kf1 = *(const bf16x8*)&Kh[(size_t)(kbase + j * 16 + l15) * DH +
                                       32 + l4 * 8];
      s[j] = __builtin_amdgcn_mfma_f32_16x16x32_bf16(qf0, kf0, s[j], 0, 0, 0);
      s[j] = __builtin_amdgcn_mfma_f32_16x16x32_bf16(qf1, kf1, s[j], 0, 0, 0);
    }
    // scale + causal mask (last chunk contains the diagonal)
#pragma unroll
    for (int j = 0; j < 4; j++) {
      s[j][0] *= 0.125f; s[j][1] *= 0.125f;
      s[j][2] *= 0.125f; s[j][3] *= 0.125f;
    }
    if (ch == nc - 1) {
#pragma unroll
      for (int j = 0; j < 4; j++) {
        int kg = kbase + j * 16 + l15;
#pragma unroll
        for (int r = 0; r < 4; r++) {
          int qg = qbase + rbase + r;
          if (kg > qg) s[j][r] = -1e30f;
        }
      }
    }
    // ---- online softmax per row (16-lane groups share rows) ----
#pragma unroll
    for (int r = 0; r < 4; r++) {
      float rm = fmaxf(fmaxf(s[0][r], s[1][r]), fmaxf(s[2][r], s[3][r]));
      rm = fmaxf(rm, __shfl_xor(rm, 1));
      rm = fmaxf(rm, __shfl_xor(rm, 2));
      rm = fmaxf(rm, __shfl_xor(rm, 4));
      rm = fmaxf(rm, __shfl_xor(rm, 8));
      const float mn = fmaxf(m[r], rm);
      const float corr = __expf(m[r] - mn);
      m[r] = mn;
      float rs = 0.f;
#pragma unroll
      for (int j = 0; j < 4; j++) {
        float p = __expf(s[j][r] - mn);
        s[j][r] = p;
        rs += p;
      }
      rs += __shfl_xor(rs, 1);
      rs += __shfl_xor(rs, 2);
      rs += __shfl_xor(rs, 4);
      rs += __shfl_xor(rs, 8);
      l[r] = l[r] * corr + rs;
      oacc[0][r] *= corr;
      oacc[1][r] *= corr;
      oacc[2][r] *= corr;
      oacc[3][r] *= corr;
    }
    // ---- P (bf16) to LDS re-layout; same wave, no barrier ----
#pragma unroll
    for (int j = 0; j < 4; j++)
#pragma unroll
      for (int r = 0; r < 4; r++)
        P_lds[rbase + r][j * 16 + l15] = f2bf(s[j][r]);
    // ---- PV: O[16 q][64 dh] += P @ V, 8 MFMAs ----
#pragma unroll
    for (int ks = 0; ks < 2; ks++) {
      bf16x8 pa = *(const bf16x8*)&P_lds[l15][ks * 32 + l4 * 8];
#pragma unroll
      for (int j = 0; j < 4; j++) {
        bf16x8 vf = *(const bf16x8*)&Vh[(size_t)(j * 16 + l15) * TT + kbase +
                                        ks * 32 + l4 * 8];
        oacc[j] =
            __builtin_amdgcn_mfma_f32_16x16x32_bf16(pa, vf, oacc[j], 0, 0, 0);
      }
    }
  }
  // ---- epilogue: divide by l, write bf16 [T][E] ----
#pragma unroll
  for (int r = 0; r < 4; r++) {
    const float inv = 1.f / l[r];
    const int qg = qbase + rbase + r;
#pragma unroll
    for (int j = 0; j < 4; j++)
      O[(size_t)qg * EE + h * DH + j * 16 + l15] = f2bf(oacc[j][r] * inv);
  }
}

// ---------------------------------------------------------------------------
extern "C" void kernel_launch(void* const* d_in, const int* in_sizes, int n_in,
                              void* d_out, int out_size, void* d_ws,
                              size_t ws_size, hipStream_t stream) {
  const float* x = (const float*)d_in[0];    // [2048][1024]
  const float* W1 = (const float*)d_in[1];   // [3072][1024]
  const float* W2 = (const float*)d_in[2];   // [1024][1024]
  float* out = (float*)d_out;                // [2048][1024]

  float* ws = (float*)d_ws;
  const size_t HTD = (size_t)HH * TT * DH;   // 2,097,152
  float* cs = ws;
  float* sn = cs + (size_t)TT * 32;
  u16* qb16 = (u16*)(sn + (size_t)TT * 32);  // bf16 roped q [H][T][DH]
  u16* kb16 = qb16 + HTD;                    // bf16 roped k
  u16* vt16 = kb16 + HTD;                    // bf16 v transposed [H][DH][T]
  u16* obb = vt16 + HTD;                     // bf16 attn out [T][E]
  u16* xb = obb + (size_t)TT * EE;           // bf16 inputs
  u16* w1b = xb + (size_t)TT * EE;
  u16* w2b = w1b + (size_t)3 * EE * EE;

  rope_table<<<(TT * 32) / 256, 256, 0, stream>>>(cs, sn);
  cvt_all<<<786432 / 256, 256, 0, stream>>>(x, W1, W2, xb, w1b, w2b);
  // QKV: [2048 x 3072] = x @ W1^T;  q,k roped bf16; v bf16 transposed
  gemm_mfma<1><<<dim3(3 * EE / 128, TT / 128), 256, 0, stream>>>(
      xb, w1b, nullptr, qb16, kb16, vt16, cs, sn, TT, 3 * EE, EE);
  attn_mfma<<<2048, 64, 0, stream>>>(qb16, kb16, vt16, obb);
  // proj: [2048 x 1024] = attn @ W2^T
  gemm_mfma<0><<<dim3(EE / 128, TT / 128), 256, 0, stream>>>(
      obb, w2b, out, nullptr, nullptr, nullptr, nullptr, nullptr, TT, EE, EE);
}